// Round 1
// baseline (80.513 us; speedup 1.0000x reference)
//
#include <hip/hip_runtime.h>

#ifndef M_LOG2E_F
#define M_LOG2E_F 1.4426950408889634f
#endif

#if defined(__has_builtin)
#  if __has_builtin(__builtin_amdgcn_exp2f)
#    define FAST_EXP2(x) __builtin_amdgcn_exp2f(x)
#  else
#    define FAST_EXP2(x) exp2f(x)
#  endif
#  if __has_builtin(__builtin_amdgcn_rsqf)
#    define FAST_RSQ(x) __builtin_amdgcn_rsqf(x)
#  else
#    define FAST_RSQ(x) rsqrtf(x)
#  endif
#else
#  define FAST_EXP2(x) exp2f(x)
#  define FAST_RSQ(x) rsqrtf(x)
#endif

// vortex_feature: (2, 512, 6) fp32 -> columns y, x, tau, sig, v, u
// points:         (2, 256, 256, 2) fp32
// out:            (2, 256, 256, 2) fp32
//   out[...,0] =  sum_v tau_v * exp(-r2/sig^2) * rsqrt(r2) * (p1 - x_v)
//   out[...,1] = -sum_v tau_v * exp(-r2/sig^2) * rsqrt(r2) * (p0 - y_v)
__global__ __launch_bounds__(256)
void GaussianFalloffKernel_83434034692733_kernel(
    const float* __restrict__ vortex,   // (2, 512, 6)
    const float* __restrict__ points,   // (2, 65536, 2)
    float* __restrict__ out)            // (2, 65536, 2)
{
    constexpr int NV = 512;
    constexpr int PTS_PER_BATCH = 256 * 256;
    constexpr int BLOCKS_PER_BATCH = PTS_PER_BATCH / 256;  // 256

    __shared__ float4 sv[NV];   // {y, x, tau, log2e/sig^2} per vortex, 8 KB

    const int b  = blockIdx.x / BLOCKS_PER_BATCH;
    const int pt = (blockIdx.x % BLOCKS_PER_BATCH) * 256 + threadIdx.x;

    // Stage this batch's vortices into LDS, precomputing k = log2(e)/sig^2.
    const float* __restrict__ vb = vortex + (size_t)b * NV * 6;
    for (int v = threadIdx.x; v < NV; v += 256) {
        const float y   = vb[v * 6 + 0];
        const float x   = vb[v * 6 + 1];
        const float tau = vb[v * 6 + 2];
        const float sig = vb[v * 6 + 3];
        const float k   = M_LOG2E_F / (sig * sig);
        sv[v] = make_float4(y, x, tau, k);
    }
    __syncthreads();

    const float2 p = ((const float2*)points)[(size_t)b * PTS_PER_BATCH + pt];

    float acc0 = 0.0f;
    float acc1 = 0.0f;

    #pragma unroll 8
    for (int v = 0; v < NV; ++v) {
        const float4 s = sv[v];          // wave-uniform LDS broadcast
        const float dy = p.x - s.x;      // p0 - y_v
        const float dx = p.y - s.y;      // p1 - x_v
        const float r2 = fmaf(dy, dy, dx * dx);
        const float e  = FAST_EXP2(-r2 * s.w);   // exp(-r2/sig^2)
        const float ri = FAST_RSQ(r2);           // 1/sqrt(r2)
        const float f  = s.z * e * ri;
        acc0 = fmaf(f,  dx, acc0);
        acc1 = fmaf(f, -dy, acc1);
    }

    ((float2*)out)[(size_t)b * PTS_PER_BATCH + pt] = make_float2(acc0, acc1);
}

extern "C" void kernel_launch(void* const* d_in, const int* in_sizes, int n_in,
                              void* d_out, int out_size, void* d_ws, size_t ws_size,
                              hipStream_t stream) {
    const float* vortex = (const float*)d_in[0];  // (2, 512, 6)
    const float* points = (const float*)d_in[1];  // (2, 256, 256, 2)
    float* out = (float*)d_out;                   // (2, 256, 256, 2)

    const int blocks = 2 * 256;  // 2 batches * (65536 points / 256 threads)
    GaussianFalloffKernel_83434034692733_kernel<<<blocks, 256, 0, stream>>>(
        vortex, points, out);
}

// Round 2
// 73.316 us; speedup vs baseline: 1.0982x; 1.0982x over previous
//
#include <hip/hip_runtime.h>

typedef float v2f __attribute__((ext_vector_type(2)));

#if defined(__has_builtin)
#  if __has_builtin(__builtin_amdgcn_exp2f)
#    define FAST_EXP2(x) __builtin_amdgcn_exp2f(x)
#  else
#    define FAST_EXP2(x) exp2f(x)
#  endif
#  if __has_builtin(__builtin_amdgcn_rsqf)
#    define FAST_RSQ(x) __builtin_amdgcn_rsqf(x)
#  else
#    define FAST_RSQ(x) rsqrtf(x)
#  endif
#else
#  define FAST_EXP2(x) exp2f(x)
#  define FAST_RSQ(x) rsqrtf(x)
#endif

// out[b,p,0] =  sum_v tau_v * exp(-r2/sig^2) * rsqrt(r2) * (p1 - x_v)
// out[b,p,1] = -sum_v tau_v * exp(-r2/sig^2) * rsqrt(r2) * (p0 - y_v)
//
// Split-K x4 (one wave per vortex-quarter), 2 points per thread packed into
// float2 ext-vectors so non-transcendental math maps to v_pk_*_f32.
__global__ __launch_bounds__(256, 4)
void GaussianFalloffKernel_83434034692733_kernel(
    const float* __restrict__ vortex,   // (2, 512, 6)
    const float* __restrict__ points,   // (2, 65536, 2)
    float* __restrict__ out)            // (2, 65536, 2)
{
    constexpr int NV = 512;
    constexpr int NQ = 4;                 // split-K quarters (= waves per block)
    constexpr int VQ = NV / NQ;           // 128 vortices per quarter
    constexpr int PTS_PER_BLOCK = 128;    // 64 lanes x 2 points
    constexpr int BLOCKS_PER_BATCH = 65536 / PTS_PER_BLOCK;  // 512

    __shared__ float4 sv[NV];                 // {y, x, tau, -log2e/sig^2}, 8 KB
    __shared__ v2f    red[NQ][PTS_PER_BLOCK]; // 4 KB quarter partials

    const int b    = blockIdx.x / BLOCKS_PER_BATCH;
    const int base = (blockIdx.x % BLOCKS_PER_BATCH) * PTS_PER_BLOCK;

    const int tid = threadIdx.x;
    const int q   = tid >> 6;   // wave index == vortex quarter
    const int h   = tid & 63;   // lane

    // Stage this batch's vortices into LDS with -log2(e)/sig^2 precomputed.
    const float* __restrict__ vb = vortex + (size_t)b * NV * 6;
    for (int v = tid; v < NV; v += 256) {
        const float y    = vb[v * 6 + 0];
        const float x    = vb[v * 6 + 1];
        const float tau  = vb[v * 6 + 2];
        const float sig  = vb[v * 6 + 3];
        const float negk = -1.4426950408889634f / (sig * sig);
        sv[v] = make_float4(y, x, tau, negk);
    }
    __syncthreads();

    // Two points per thread: base+h and base+h+64, packed as SoA float2.
    const float2* __restrict__ pp =
        (const float2*)points + (size_t)b * 65536 + base;
    const float2 pA = pp[h];
    const float2 pB = pp[h + 64];
    const v2f py = { pA.x, pB.x };
    const v2f px = { pA.y, pB.y };

    v2f acc0 = { 0.0f, 0.0f };
    v2f acc1 = { 0.0f, 0.0f };

    const float4* __restrict__ svq = sv + q * VQ;
    #pragma unroll 8
    for (int v = 0; v < VQ; ++v) {
        const float4 s = svq[v];            // wave-uniform LDS broadcast
        const v2f dy = py - s.x;            // p0 - y_v (both points)
        const v2f dx = px - s.y;            // p1 - x_v
        const v2f r2 = dy * dy + dx * dx;   // pk_mul + pk_fma
        const v2f t  = r2 * s.w;            // -r2/sig^2 * log2e
        v2f e, ri;
        e.x  = FAST_EXP2(t.x);  e.y  = FAST_EXP2(t.y);
        ri.x = FAST_RSQ(r2.x);  ri.y = FAST_RSQ(r2.y);
        const v2f f = (e * ri) * s.z;
        acc0 += f * dx;
        acc1 -= f * dy;
    }

    // Cross-quarter reduction through LDS.
    red[q][h]      = (v2f){ acc0.x, acc1.x };   // point base+h
    red[q][h + 64] = (v2f){ acc0.y, acc1.y };   // point base+h+64
    __syncthreads();

    if (tid < PTS_PER_BLOCK) {
        const v2f s0 = red[0][tid] + red[1][tid] + red[2][tid] + red[3][tid];
        ((float2*)out)[(size_t)b * 65536 + base + tid] = make_float2(s0.x, s0.y);
    }
}

extern "C" void kernel_launch(void* const* d_in, const int* in_sizes, int n_in,
                              void* d_out, int out_size, void* d_ws, size_t ws_size,
                              hipStream_t stream) {
    const float* vortex = (const float*)d_in[0];  // (2, 512, 6)
    const float* points = (const float*)d_in[1];  // (2, 256, 256, 2)
    float* out = (float*)d_out;                   // (2, 256, 256, 2)

    const int blocks = 2 * (65536 / 128);  // 1024
    GaussianFalloffKernel_83434034692733_kernel<<<blocks, 256, 0, stream>>>(
        vortex, points, out);
}